// Round 13
// baseline (154.318 us; speedup 1.0000x reference)
//
#include <hip/hip_runtime.h>
#include <hip/hip_bf16.h>
#include <math.h>

typedef __attribute__((ext_vector_type(8))) short bf16x8;
typedef __attribute__((ext_vector_type(4))) short bf16x4;
typedef __attribute__((ext_vector_type(4))) float f32x4;
typedef __attribute__((ext_vector_type(4))) int   i32x4;

#define NHh 16
#define Sq  2048
#define HIDq 1024
#define HDq 64
#define LOG2E 1.4426950408889634f

#if __has_builtin(__builtin_amdgcn_exp2f)
#define EXP2F(x) __builtin_amdgcn_exp2f(x)
#else
#define EXP2F(x) exp2f(x)
#endif
#if __has_builtin(__builtin_amdgcn_rcpf)
#define RCPF(x) __builtin_amdgcn_rcpf(x)
#else
#define RCPF(x) (1.0f/(x))
#endif

// 16x16x16 bf16 MFMA: D[q][d] += A[q][k]*B[k][d]
#if __has_builtin(__builtin_amdgcn_mfma_f32_16x16x16bf16_1k)
__device__ __forceinline__ f32x4 MFMA16(bf16x4 a, bf16x4 b, f32x4 c){
  return __builtin_amdgcn_mfma_f32_16x16x16bf16_1k(a, b, c, 0, 0, 0);
}
#else
__device__ __forceinline__ f32x4 MFMA16(bf16x4 a, bf16x4 b, f32x4 c){
  asm volatile("v_mfma_f32_16x16x16_bf16 %0, %1, %2, %0\n\ts_nop 7\n\ts_nop 7"
               : "+v"(c) : "v"(a), "v"(b));
  return c;
}
#endif

__device__ __forceinline__ unsigned short f2bf(float f){
  union { float f; unsigned u; } v; v.f = f;
  unsigned r = v.u + 0x7fffu + ((v.u >> 16) & 1u);   // RNE
  return (unsigned short)(r >> 16);
}
__device__ __forceinline__ float bf2f(unsigned short s){
  union { unsigned u; float f; } v; v.u = ((unsigned)s) << 16;
  return v.f;
}
__device__ __forceinline__ unsigned pk2bf(float lo, float hi){
  union { __hip_bfloat162 h; unsigned u; } w;
  w.h = __float22bfloat162_rn(make_float2(lo, hi));
  return w.u;
}

// async global->LDS, 16B per lane; LDS dest = wave-uniform base + lane*16 (linear)
__device__ __forceinline__ void gload_lds16(const unsigned short* g, unsigned short* l){
  __builtin_amdgcn_global_load_lds(
      (const __attribute__((address_space(1))) unsigned int*)g,
      (__attribute__((address_space(3))) unsigned int*)l, 16, 0, 0);
}

// ---------------- convert x (f32 -> bf16) + mask -> bf16 0/1 tail ----------------
__global__ __launch_bounds__(256) void convert_x(const float* __restrict__ in,
                                                 unsigned short* __restrict__ out, int n8,
                                                 const int* __restrict__ mask,
                                                 unsigned short* __restrict__ Mbf){
  int bid = blockIdx.x;
  int nmain = gridDim.x - 2;
  if (bid >= nmain){
    int base = (bid - nmain)*2048 + threadIdx.x*8;
    #pragma unroll
    for (int j=0;j<8;j++) Mbf[base+j] = mask[base+j] ? (unsigned short)0x3F80 : (unsigned short)0;
    return;
  }
  int i = bid*256 + threadIdx.x;
  if (i >= n8) return;
  const f32x4* p = (const f32x4*)(in + (size_t)i*8);
  f32x4 a = p[0], b = p[1];
  union { unsigned short us[8]; i32x4 v; } o;
  #pragma unroll
  for (int j=0;j<4;j++){ o.us[j] = f2bf(a[j]); o.us[4+j] = f2bf(b[j]); }
  *(i32x4*)(out + (size_t)i*8) = o.v;
}

// ------------- transpose+convert weights: w[K][N] f32 -> wT[N][K] bf16 -------------
__global__ __launch_bounds__(256) void transpose_w(const float* __restrict__ w0, const float* __restrict__ w1,
                                                   const float* __restrict__ w2, const float* __restrict__ w3,
                                                   unsigned short* __restrict__ wT){
  __shared__ float tile[32][33];
  int z = blockIdx.z;
  const float* w = (z==0)?w0:(z==1)?w1:(z==2)?w2:w3;
  unsigned short* dst = wT + (size_t)z*HIDq*HIDq;
  int tx = threadIdx.x, ty = threadIdx.y;
  int n0 = blockIdx.x*32, k0 = blockIdx.y*32;
  #pragma unroll
  for (int i=ty;i<32;i+=8) tile[i][tx] = w[(size_t)(k0+i)*HIDq + n0+tx];
  __syncthreads();
  #pragma unroll
  for (int i=ty;i<32;i+=8) dst[(size_t)(n0+i)*HIDq + k0+tx] = f2bf(tile[tx][i]);
}

// ------------- GEMM main loop: gload_lds, BK=64, granule-XOR swizzled LDS (T2) -------------
__device__ __forceinline__ void gemm_core_gl(const unsigned short* __restrict__ Ag,
                                             const unsigned short* __restrict__ Bg,
                                             unsigned short* As, unsigned short* Bs,
                                             int t, int wv, int lane, int wr, int wc, int lr, int g,
                                             f32x4 acc[4][4]){
  for (int k0=0; k0<HIDq; k0+=64){
    __syncthreads();
    #pragma unroll
    for (int j=0;j<4;j++){
      int flat = (j*4+wv)*64 + lane;
      int row = flat>>3, c = flat&7;
      int srcc = (c ^ (row&7))*8;
      gload_lds16(Ag + (size_t)row*HIDq + k0 + srcc, &As[flat*8]);
      gload_lds16(Bg + (size_t)row*HIDq + k0 + srcc, &Bs[flat*8]);
    }
    __syncthreads();
    #pragma unroll
    for (int ks=0; ks<2; ks++){
      bf16x8 af[4], bfv[4];
      #pragma unroll
      for (int m=0;m<4;m++){
        int rr = wr + m*16 + lr;
        af[m]  = *(bf16x8*)&As[rr*64 + (((ks*4+g) ^ (rr&7))*8)];
      }
      #pragma unroll
      for (int n=0;n<4;n++){
        int rr = wc + n*16 + lr;
        bfv[n] = *(bf16x8*)&Bs[rr*64 + (((ks*4+g) ^ (rr&7))*8)];
      }
      #pragma unroll
      for (int n=0;n<4;n++)
        #pragma unroll
        for (int m=0;m<4;m++)
          acc[n][m] = __builtin_amdgcn_mfma_f32_16x16x32_bf16(bfv[n], af[m], acc[n][m], 0,0,0);
    }
  }
}

// ------------- fused QKV projection (V rows pre-masked) -------------
__global__ __launch_bounds__(256) void gemm_qkv(const unsigned short* __restrict__ xbf,
    const unsigned short* __restrict__ wT,
    const float* __restrict__ q_b, const float* __restrict__ k_b, const float* __restrict__ v_b,
    const int* __restrict__ mask,
    unsigned short* __restrict__ Qeff, unsigned short* __restrict__ Keff,
    unsigned short* __restrict__ Vt){
  __shared__ unsigned short As[128*64];
  __shared__ unsigned short Bs[128*64];
  const int t = threadIdx.x;
  const int wv = t>>6, lane = t&63, g = lane>>4, lr = lane&15;
  const int wr = (wv>>1)*64, wc = (wv&1)*64;
  f32x4 acc[4][4] = {};
  const int xb = blockIdx.x, yb = blockIdx.y;
  const float VS = 0.25501335f;   // log2e / sqrt(32)

  if (xb < 16){
    const int row0 = yb*128, col0 = xb*128;
    gemm_core_gl(xbf + (size_t)row0*HIDq, wT + (size_t)col0*HIDq, As, Bs, t, wv, lane, wr, wc, lr, g, acc);
    #pragma unroll
    for (int n=0;n<4;n++){
      #pragma unroll
      for (int m=0;m<4;m++){
        int row = row0 + wr + m*16 + lr;
        int b_ = row>>11, ss = row&2047;
        int colb = col0 + wc + n*16 + g*4;
        int seg = colb>>10, cw = colb&1023;
        int hh = cw>>6, d = cw&63;
        const float* bp = seg ? k_b : q_b;
        f32x4 bb = *(const f32x4*)&bp[cw];
        float sc = seg ? 1.0f : (d < 32 ? VS : -LOG2E);
        unsigned short* E = seg ? Keff : Qeff;
        float v0 = (acc[n][m][0]+bb[0])*sc, v1 = (acc[n][m][1]+bb[1])*sc;
        float v2 = (acc[n][m][2]+bb[2])*sc, v3 = (acc[n][m][3]+bb[3])*sc;
        union { unsigned u[2]; unsigned long long ll; } W;
        W.u[0] = pk2bf(v0,v1); W.u[1] = pk2bf(v2,v3);
        *(unsigned long long*)&E[(((size_t)b_*NHh+hh)*Sq+ss)*HDq + d] = W.ll;
      }
    }
  } else {
    const int row0 = (xb-16)*128, col0 = yb*128;
    gemm_core_gl(wT + (size_t)2*HIDq*HIDq + (size_t)row0*HIDq, xbf + (size_t)col0*HIDq,
                 As, Bs, t, wv, lane, wr, wc, lr, g, acc);
    #pragma unroll
    for (int n=0;n<4;n++){
      #pragma unroll
      for (int m=0;m<4;m++){
        int chan = row0 + wr + m*16 + lr;
        int hh = chan>>6, d = chan&63;
        float bv = v_b[chan];
        int colb = col0 + wc + n*16 + g*4;
        int b_ = colb>>11, ss = colb&2047;
        i32x4 mk = *(const i32x4*)&mask[(size_t)b_*Sq + ss];   // zero masked V rows
        float m0 = mk[0]?1.f:0.f, m1 = mk[1]?1.f:0.f, m2 = mk[2]?1.f:0.f, m3 = mk[3]?1.f:0.f;
        union { unsigned u[2]; unsigned long long ll; } W;
        W.u[0] = pk2bf((acc[n][m][0]+bv)*m0, (acc[n][m][1]+bv)*m1);
        W.u[1] = pk2bf((acc[n][m][2]+bv)*m2, (acc[n][m][3]+bv)*m3);
        *(unsigned long long*)&Vt[(((size_t)b_*NHh+hh)*HDq + d)*Sq + ss] = W.ll;
      }
    }
  }
}

// ------------- output projection: 128x64 tile, grid 512 (2 blocks/CU) -------------
__global__ __launch_bounds__(256) void gemm_out(const unsigned short* __restrict__ A,
                                                const unsigned short* __restrict__ Bt,
                                                const float* __restrict__ bias,
                                                float* __restrict__ C){
  __shared__ unsigned short As[128*64];   // 16 KB
  __shared__ unsigned short Bs[64*64];    // 8 KB
  const int t = threadIdx.x;
  const int wv = t>>6, lane = t&63, g = lane>>4, lr = lane&15;
  const int wr = (wv>>1)*64, wc = (wv&1)*32;
  const int row0 = blockIdx.y*128, col0 = blockIdx.x*64;
  f32x4 acc[2][4] = {};
  for (int k0=0; k0<HIDq; k0+=64){
    __syncthreads();
    #pragma unroll
    for (int j=0;j<4;j++){
      int flat = t + j*256;
      int row = flat>>3, c = flat&7;
      int srcc = (c ^ (row&7))*8;
      gload_lds16(A + (size_t)(row0+row)*HIDq + k0 + srcc, &As[flat*8]);
    }
    #pragma unroll
    for (int j=0;j<2;j++){
      int flat = t + j*256;
      int row = flat>>3, c = flat&7;
      int srcc = (c ^ (row&7))*8;
      gload_lds16(Bt + (size_t)(col0+row)*HIDq + k0 + srcc, &Bs[flat*8]);
    }
    __syncthreads();
    #pragma unroll
    for (int ks=0; ks<2; ks++){
      bf16x8 af[4], bfv[2];
      #pragma unroll
      for (int m=0;m<4;m++){
        int rr = wr + m*16 + lr;
        af[m]  = *(bf16x8*)&As[rr*64 + (((ks*4+g) ^ (rr&7))*8)];
      }
      #pragma unroll
      for (int n=0;n<2;n++){
        int rr = wc + n*16 + lr;
        bfv[n] = *(bf16x8*)&Bs[rr*64 + (((ks*4+g) ^ (rr&7))*8)];
      }
      #pragma unroll
      for (int n=0;n<2;n++)
        #pragma unroll
        for (int m=0;m<4;m++)
          acc[n][m] = __builtin_amdgcn_mfma_f32_16x16x32_bf16(bfv[n], af[m], acc[n][m], 0,0,0);
    }
  }
  #pragma unroll
  for (int n=0;n<2;n++){
    #pragma unroll
    for (int m=0;m<4;m++){
      int row = row0 + wr + m*16 + lr;
      int colb = col0 + wc + n*16 + g*4;
      f32x4 bb = *(const f32x4*)&bias[colb];
      f32x4 o = acc[n][m] + bb;
      *(f32x4*)&C[(size_t)row*HIDq + colb] = o;
    }
  }
}

// ------------- flash attention: 4 waves x q32 (2 groups), q-tile 128, 2K+2V dbuf -------------
// Every kf/vf LDS fragment read serves TWO q-groups -> per-CU LDS traffic halves.
// Mask row resident in LDS (4 KB). Exact counted vmcnt: stage K(i+1),V(i+1) then
// vmcnt(4) => K(i),V(i) (issued prev phase, 4 newer ops) guaranteed landed.
__global__ __launch_bounds__(256,2) void attn_kernel(
    const unsigned short* __restrict__ Qe, const unsigned short* __restrict__ Ke,
    const unsigned short* __restrict__ Vt, const float* __restrict__ Tb,
    const float* __restrict__ tbias, const unsigned short* __restrict__ Mbf,
    unsigned short* __restrict__ Obuf)
{
  __shared__ __align__(16) unsigned char smem[36864];
  unsigned short* Kb0 = (unsigned short*)smem;             // 8 KB each
  unsigned short* Kb1 = (unsigned short*)(smem + 8192);
  unsigned short* Vb0 = (unsigned short*)(smem + 16384);
  unsigned short* Vb1 = (unsigned short*)(smem + 24576);
  unsigned short* Msk = (unsigned short*)(smem + 32768);   // 2048 bf16 = 4 KB
  float* qls = (float*)smem;                               // overlay 16.9 KB (Kb0,Kb1,+512B Vb0)
  unsigned short* qtls = (unsigned short*)(smem + 24576);  // overlay 10.2 KB (Vb1 + Msk head)

  const int t = threadIdx.x;
  // XCD-aware decode: 16 q-blocks x 4 bh per XCD
  const int dd = blockIdx.x;
  const int slot = dd>>3, xcd = dd&7;
  const int x = slot & 15;
  const int bh = ((slot>>4)<<3) | xcd;
  const int h = bh & 15, b = bh >> 4;
  const int q0 = x*128;
  const int wv = t>>6, lane = t&63, g = lane>>4, lr = lane&15;

  const unsigned short* Qb  = Qe + (((size_t)b*NHh+h)*Sq + q0)*HDq;
  const unsigned short* Kb  = Ke + ((size_t)b*NHh+h)*(size_t)Sq*HDq;
  const unsigned short* Vtb = Vt + ((size_t)b*NHh+h)*(size_t)HDq*Sq;
  const unsigned short* Mbfb = Mbf + (size_t)b*Sq;

  // ---- prologue: qt = q_type(-log2e-scaled) @ T[h] for 128 rows ----
  {
    int row = t>>1, c8 = (t&1)*16;
    bf16x8 v0 = *(const bf16x8*)(Qb + (size_t)row*HDq + 32 + c8);
    bf16x8 v1 = *(const bf16x8*)(Qb + (size_t)row*HDq + 32 + c8 + 8);
    #pragma unroll
    for (int j=0;j<8;j++){
      qls[row*33 + c8 + j]     = bf2f((unsigned short)v0[j]);
      qls[row*33 + c8 + 8 + j] = bf2f((unsigned short)v1[j]);
    }
  }
  __syncthreads();
  {
    const float* Th = Tb + (size_t)h*1024;
    #pragma unroll
    for (int rp=0; rp<2; rp++){
      int row = rp*64 + (t&63), e0 = (t>>6)*8;
      float a[8] = {};
      #pragma unroll 4
      for (int d=0; d<32; d++){
        float qd = qls[row*33 + d];
        const f32x4* tp = (const f32x4*)(Th + d*32 + e0);
        f32x4 t0 = tp[0], t1 = tp[1];
        a[0]+=qd*t0[0]; a[1]+=qd*t0[1]; a[2]+=qd*t0[2]; a[3]+=qd*t0[3];
        a[4]+=qd*t1[0]; a[5]+=qd*t1[1]; a[6]+=qd*t1[2]; a[7]+=qd*t1[3];
      }
      union { unsigned u[2]; unsigned long long ll; } W0, W1;
      W0.u[0]=pk2bf(a[0],a[1]); W0.u[1]=pk2bf(a[2],a[3]);
      W1.u[0]=pk2bf(a[4],a[5]); W1.u[1]=pk2bf(a[6],a[7]);
      *(unsigned long long*)&qtls[row*40 + e0]     = W0.ll;
      *(unsigned long long*)&qtls[row*40 + e0 + 4] = W1.ll;
    }
  }
  bf16x8 qvf0 = *(const bf16x8*)(Qb + (size_t)(wv*32+lr)*HDq + g*8);      // val half, group 0
  bf16x8 qvf1 = *(const bf16x8*)(Qb + (size_t)(wv*32+16+lr)*HDq + g*8);   // group 1
  __syncthreads();   // qtls writes visible
  bf16x8 qtn0 = *(const bf16x8*)&qtls[(wv*32+lr)*40 + g*8];
  bf16x8 qtn1 = *(const bf16x8*)&qtls[(wv*32+16+lr)*40 + g*8];
  __syncthreads();   // all overlay reads done before staging overwrites

  // ---- stage mask row (4 KB) + K(0)->Kb0 + V(0)->Vb0; drain once ----
  gload_lds16(Mbfb + t*8, Msk + t*8);
  #pragma unroll
  for (int i=0;i<2;i++){
    int c = t + i*256;
    int kr = c>>3, kc = c&7;
    gload_lds16(Kb + (size_t)kr*HDq + ((kc ^ (kr&7))*8), Kb0 + c*8);
    int vd = c>>3, vc = c&7;
    gload_lds16(Vtb + (size_t)vd*Sq + ((vc ^ (vd&7))*8), Vb0 + c*8);
  }
  __syncthreads();   // full drain at block start only

  const float tbn = -tbias[h]*LOG2E;
  const f32x4 tbc = {tbn,tbn,tbn,tbn};
  const f32x4 zf = {0.f,0.f,0.f,0.f};
  f32x4 oT0[4] = {}, oT1[4] = {};           // oT_G[db][r] = O[q=G*16+4g+r][d=db*16+lr]
  f32x4 lsum0 = {0.f,0.f,0.f,0.f}, lsum1 = {0.f,0.f,0.f,0.f};

  auto phase = [&](const unsigned short* Kc, const unsigned short* Vc, int key0,
                   bool doStage, int keyN, unsigned short* Kn, unsigned short* Vn){
    if (doStage){
      #pragma unroll
      for (int i=0;i<2;i++){
        int c = t + i*256;
        int kr = c>>3, kc = c&7;
        gload_lds16(Kb + (size_t)(keyN+kr)*HDq + ((kc ^ (kr&7))*8), Kn + c*8);
        int vd = c>>3, vc = c&7;
        gload_lds16(Vtb + (size_t)vd*Sq + keyN + ((vc ^ (vd&7))*8), Vn + c*8);
      }
      asm volatile("s_waitcnt vmcnt(4)" ::: "memory");   // K(i),V(i) retired (4 newer in flight)
    } else {
      asm volatile("s_waitcnt vmcnt(0)" ::: "memory");
    }
    __builtin_amdgcn_sched_barrier(0);
    __builtin_amdgcn_s_barrier();

    // QK^T swapped, both q-groups share kf0/kf1
    f32x4 sv0[4], st0[4], sv1[4], st1[4];
    __builtin_amdgcn_s_setprio(1);
    #pragma unroll
    for (int ks=0; ks<4; ks++){
      const unsigned short* kb = Kc + (ks*16+lr)*64;
      bf16x8 kf0 = *(const bf16x8*)(kb + (((g  ) ^ (lr&7))*8));
      bf16x8 kf1 = *(const bf16x8*)(kb + (((4+g) ^ (lr&7))*8));
      sv0[ks] = __builtin_amdgcn_mfma_f32_16x16x32_bf16(kf0, qvf0, zf, 0,0,0);
      st0[ks] = __builtin_amdgcn_mfma_f32_16x16x32_bf16(kf1, qtn0, tbc, 0,0,0);
      sv1[ks] = __builtin_amdgcn_mfma_f32_16x16x32_bf16(kf0, qvf1, zf, 0,0,0);
      st1[ks] = __builtin_amdgcn_mfma_f32_16x16x32_bf16(kf1, qtn1, tbc, 0,0,0);
    }
    __builtin_amdgcn_s_setprio(0);
    // softmax both groups: p = exp2(sv) * sigmoid2(st)
    bf16x4 pa0[4], pa1[4];
    #pragma unroll
    for (int ks=0; ks<4; ks++){
      {
        float p0 = EXP2F(sv0[ks][0]) * RCPF(1.f + EXP2F(st0[ks][0]));
        float p1 = EXP2F(sv0[ks][1]) * RCPF(1.f + EXP2F(st0[ks][1]));
        float p2 = EXP2F(sv0[ks][2]) * RCPF(1.f + EXP2F(st0[ks][2]));
        float p3 = EXP2F(sv0[ks][3]) * RCPF(1.f + EXP2F(st0[ks][3]));
        union { unsigned u[2]; bf16x4 v; } P_;
        P_.u[0] = pk2bf(p0,p1); P_.u[1] = pk2bf(p2,p3);
        pa0[ks] = P_.v;
      }
      {
        float p0 = EXP2F(sv1[ks][0]) * RCPF(1.f + EXP2F(st1[ks][0]));
        float p1 = EXP2F(sv1[ks][1]) * RCPF(1.f + EXP2F(st1[ks][1]));
        float p2 = EXP2F(sv1[ks][2]) * RCPF(1.f + EXP2F(st1[ks][2]));
        float p3 = EXP2F(sv1[ks][3]) * RCPF(1.f + EXP2F(st1[ks][3]));
        union { unsigned u[2]; bf16x4 v; } P_;
        P_.u[0] = pk2bf(p0,p1); P_.u[1] = pk2bf(p2,p3);
        pa1[ks] = P_.v;
      }
    }
    // PV: vf read once, used by both groups; lsum via LDS mask fragment (broadcast)
    #pragma unroll
    for (int ks=0; ks<4; ks++){
      bf16x4 mfr = *(const bf16x4*)(Msk + key0 + ks*16 + g*4);
      __builtin_amdgcn_s_setprio(1);
      lsum0 = MFMA16(pa0[ks], mfr, lsum0);
      lsum1 = MFMA16(pa1[ks], mfr, lsum1);
      #pragma unroll
      for (int db=0; db<4; db++){
        bf16x4 vf = *(const bf16x4*)(Vc + (db*16+lr)*64 + (((2*ks + (g>>1)) ^ (lr&7))*8 + 4*(g&1)));
        oT0[db] = MFMA16(pa0[ks], vf, oT0[db]);
        oT1[db] = MFMA16(pa1[ks], vf, oT1[db]);
      }
      __builtin_amdgcn_s_setprio(0);
    }
    __builtin_amdgcn_s_barrier();      // readers done before bufs reused
  };

  for (int kt=0; kt<Sq; kt+=128){
    phase(Kb0, Vb0, kt,      true,           kt+64,  Kb1, Vb1);
    phase(Kb1, Vb1, kt+64,   kt+128 < Sq,    kt+128, Kb0, Vb0);
  }

  // ---- epilogue ----
  float linv0[4], linv1[4];
  #pragma unroll
  for (int r=0;r<4;r++){
    linv0[r] = (lsum0[r] > 0.f) ? RCPF(lsum0[r]) : 0.f;
    linv1[r] = (lsum1[r] > 0.f) ? RCPF(lsum1[r]) : 0.f;
  }
  {
    unsigned short* Ob = Obuf + ((size_t)b*Sq + (q0 + wv*32 + g*4))*HIDq + h*HDq + lr;
    #pragma unroll
    for (int db=0; db<4; db++)
      #pragma unroll
      for (int r=0;r<4;r++)
        Ob[(size_t)r*HIDq + db*16] = f2bf(oT0[db][r]*linv0[r]);
  }
  {
    unsigned short* Ob = Obuf + ((size_t)b*Sq + (q0 + wv*32 + 16 + g*4))*HIDq + h*HDq + lr;
    #pragma unroll
    for (int db=0; db<4; db++)
      #pragma unroll
      for (int r=0;r<4;r++)
        Ob[(size_t)r*HIDq + db*16] = f2bf(oT1[db][r]*linv1[r]);
  }
}

extern "C" void kernel_launch(void* const* d_in, const int* in_sizes, int n_in,
                              void* d_out, int out_size, void* d_ws, size_t ws_size,
                              hipStream_t stream) {
  const float* x     = (const float*)d_in[0];
  const float* q_w   = (const float*)d_in[1];
  const float* q_b   = (const float*)d_in[2];
  const float* k_w   = (const float*)d_in[3];
  const float* k_b   = (const float*)d_in[4];
  const float* v_w   = (const float*)d_in[5];
  const float* v_b   = (const float*)d_in[6];
  const float* out_w = (const float*)d_in[7];
  const float* out_b = (const float*)d_in[8];
  const float* Tb    = (const float*)d_in[9];
  const float* tbias = (const float*)d_in[10];
  const int*   mask  = (const int*)d_in[11];

  const size_t MROWS = 4096;             // B*S
  unsigned short* xbf  = (unsigned short*)d_ws;           // 4M shorts
  unsigned short* wT   = xbf  + MROWS*HIDq;               // 4 x 1M
  unsigned short* Qeff = wT   + (size_t)4*HIDq*HIDq;      // (B,NH,S,HD), prescaled
  unsigned short* Keff = Qeff + MROWS*HIDq;
  unsigned short* Vt   = Keff + MROWS*HIDq;               // (B,NH,HD,S) transposed, masked rows zeroed
  unsigned short* Obuf = Vt   + MROWS*HIDq;               // (B,S,HID) bf16
  unsigned short* Mbf  = Obuf + MROWS*HIDq;               // (B,S) bf16 0/1 mask

  int n8 = (int)(MROWS*HIDq/8);
  convert_x<<<dim3(n8/256 + 2), dim3(256), 0, stream>>>(x, xbf, n8, mask, Mbf);
  transpose_w<<<dim3(32,32,4), dim3(32,8), 0, stream>>>(q_w, k_w, v_w, out_w, wT);

  gemm_qkv<<<dim3(24,32), dim3(256), 0, stream>>>(xbf, wT, q_b, k_b, v_b, mask, Qeff, Keff, Vt);

  attn_kernel<<<dim3(512), dim3(256), 0, stream>>>(Qeff, Keff, Vt, Tb, tbias, Mbf, Obuf);

  gemm_out<<<dim3(16,32), dim3(256), 0, stream>>>(Obuf, wT + (size_t)3*HIDq*HIDq, out_b, (float*)d_out);
}

// Round 14
// 148.978 us; speedup vs baseline: 1.0358x; 1.0358x over previous
//
#include <hip/hip_runtime.h>
#include <hip/hip_bf16.h>
#include <math.h>

typedef __attribute__((ext_vector_type(8))) short bf16x8;
typedef __attribute__((ext_vector_type(4))) short bf16x4;
typedef __attribute__((ext_vector_type(4))) float f32x4;
typedef __attribute__((ext_vector_type(4))) int   i32x4;

#define NHh 16
#define Sq  2048
#define HIDq 1024
#define HDq 64
#define LOG2E 1.4426950408889634f

#if __has_builtin(__builtin_amdgcn_exp2f)
#define EXP2F(x) __builtin_amdgcn_exp2f(x)
#else
#define EXP2F(x) exp2f(x)
#endif
#if __has_builtin(__builtin_amdgcn_rcpf)
#define RCPF(x) __builtin_amdgcn_rcpf(x)
#else
#define RCPF(x) (1.0f/(x))
#endif

// 16x16x16 bf16 MFMA: D[q][d] += A[q][k]*B[k][d]
#if __has_builtin(__builtin_amdgcn_mfma_f32_16x16x16bf16_1k)
__device__ __forceinline__ f32x4 MFMA16(bf16x4 a, bf16x4 b, f32x4 c){
  return __builtin_amdgcn_mfma_f32_16x16x16bf16_1k(a, b, c, 0, 0, 0);
}
#else
__device__ __forceinline__ f32x4 MFMA16(bf16x4 a, bf16x4 b, f32x4 c){
  asm volatile("v_mfma_f32_16x16x16_bf16 %0, %1, %2, %0\n\ts_nop 7\n\ts_nop 7"
               : "+v"(c) : "v"(a), "v"(b));
  return c;
}
#endif

__device__ __forceinline__ unsigned short f2bf(float f){
  union { float f; unsigned u; } v; v.f = f;
  unsigned r = v.u + 0x7fffu + ((v.u >> 16) & 1u);   // RNE
  return (unsigned short)(r >> 16);
}
__device__ __forceinline__ float bf2f(unsigned short s){
  union { unsigned u; float f; } v; v.u = ((unsigned)s) << 16;
  return v.f;
}
__device__ __forceinline__ unsigned pk2bf(float lo, float hi){
  union { __hip_bfloat162 h; unsigned u; } w;
  w.h = __float22bfloat162_rn(make_float2(lo, hi));
  return w.u;
}

// async global->LDS, 16B per lane; LDS dest = wave-uniform base + lane*16 (linear)
__device__ __forceinline__ void gload_lds16(const unsigned short* g, unsigned short* l){
  __builtin_amdgcn_global_load_lds(
      (const __attribute__((address_space(1))) unsigned int*)g,
      (__attribute__((address_space(3))) unsigned int*)l, 16, 0, 0);
}

// ------------- fused prep: x f32->bf16 convert | mask->bf16 | 4x weight transpose -------------
// blocks [0,2048): convert x; [2048,2050): mask; [2050,6146): transpose (z = (bid-2050)>>10)
__global__ __launch_bounds__(256) void prep(const float* __restrict__ x,
                                            unsigned short* __restrict__ xbf,
                                            const int* __restrict__ mask,
                                            unsigned short* __restrict__ Mbf,
                                            const float* __restrict__ w0, const float* __restrict__ w1,
                                            const float* __restrict__ w2, const float* __restrict__ w3,
                                            unsigned short* __restrict__ wT){
  int bid = blockIdx.x;
  int t = threadIdx.x;
  if (bid < 2048){
    int i = bid*256 + t;
    const f32x4* p = (const f32x4*)(x + (size_t)i*8);
    f32x4 a = p[0], b = p[1];
    union { unsigned short us[8]; i32x4 v; } o;
    #pragma unroll
    for (int j=0;j<4;j++){ o.us[j] = f2bf(a[j]); o.us[4+j] = f2bf(b[j]); }
    *(i32x4*)(xbf + (size_t)i*8) = o.v;
  } else if (bid < 2050){
    int base = (bid - 2048)*2048 + t*8;
    #pragma unroll
    for (int j=0;j<8;j++) Mbf[base+j] = mask[base+j] ? (unsigned short)0x3F80 : (unsigned short)0;
  } else {
    __shared__ float tile[32][33];
    int bid2 = bid - 2050;
    int z = bid2 >> 10, rem = bid2 & 1023;
    int bx = rem & 31, by = rem >> 5;
    const float* w = (z==0)?w0:(z==1)?w1:(z==2)?w2:w3;
    unsigned short* dst = wT + (size_t)z*HIDq*HIDq;
    int tx = t & 31, ty = t >> 5;
    int n0 = bx*32, k0 = by*32;
    #pragma unroll
    for (int i=ty;i<32;i+=8) tile[i][tx] = w[(size_t)(k0+i)*HIDq + n0+tx];
    __syncthreads();
    #pragma unroll
    for (int i=ty;i<32;i+=8) dst[(size_t)(n0+i)*HIDq + k0+tx] = f2bf(tile[tx][i]);
  }
}

// ------------- GEMM main loop: gload_lds, BK=64, granule-XOR swizzled LDS (T2) -------------
__device__ __forceinline__ void gemm_core_gl(const unsigned short* __restrict__ Ag,
                                             const unsigned short* __restrict__ Bg,
                                             unsigned short* As, unsigned short* Bs,
                                             int t, int wv, int lane, int wr, int wc, int lr, int g,
                                             f32x4 acc[4][4]){
  for (int k0=0; k0<HIDq; k0+=64){
    __syncthreads();
    #pragma unroll
    for (int j=0;j<4;j++){
      int flat = (j*4+wv)*64 + lane;
      int row = flat>>3, c = flat&7;
      int srcc = (c ^ (row&7))*8;
      gload_lds16(Ag + (size_t)row*HIDq + k0 + srcc, &As[flat*8]);
      gload_lds16(Bg + (size_t)row*HIDq + k0 + srcc, &Bs[flat*8]);
    }
    __syncthreads();
    #pragma unroll
    for (int ks=0; ks<2; ks++){
      bf16x8 af[4], bfv[4];
      #pragma unroll
      for (int m=0;m<4;m++){
        int rr = wr + m*16 + lr;
        af[m]  = *(bf16x8*)&As[rr*64 + (((ks*4+g) ^ (rr&7))*8)];
      }
      #pragma unroll
      for (int n=0;n<4;n++){
        int rr = wc + n*16 + lr;
        bfv[n] = *(bf16x8*)&Bs[rr*64 + (((ks*4+g) ^ (rr&7))*8)];
      }
      #pragma unroll
      for (int n=0;n<4;n++)
        #pragma unroll
        for (int m=0;m<4;m++)
          acc[n][m] = __builtin_amdgcn_mfma_f32_16x16x32_bf16(bfv[n], af[m], acc[n][m], 0,0,0);
    }
  }
}

// ------------- fused QKV projection (V rows pre-masked), XCD weight-panel colocation -------------
__global__ __launch_bounds__(256) void gemm_qkv(const unsigned short* __restrict__ xbf,
    const unsigned short* __restrict__ wT,
    const float* __restrict__ q_b, const float* __restrict__ k_b, const float* __restrict__ v_b,
    const int* __restrict__ mask,
    unsigned short* __restrict__ Qeff, unsigned short* __restrict__ Keff,
    unsigned short* __restrict__ Vt){
  __shared__ unsigned short As[128*64];
  __shared__ unsigned short Bs[128*64];
  const int t = threadIdx.x;
  const int wv = t>>6, lane = t&63, g = lane>>4, lr = lane&15;
  const int wr = (wv>>1)*64, wc = (wv&1)*64;
  f32x4 acc[4][4] = {};
  // XCD colocation: blocks sharing a weight panel (same xb) land on one XCD (3 panels/XCD)
  const int bid = blockIdx.x;
  const int xcd = bid & 7, idx = bid >> 3;          // idx in [0,96)
  const int xb = (idx % 3)*8 + xcd;                 // [0,24) bijective
  const int yb = idx / 3;                           // [0,32)
  const float VS = 0.25501335f;   // log2e / sqrt(32)

  if (xb < 16){
    const int row0 = yb*128, col0 = xb*128;
    gemm_core_gl(xbf + (size_t)row0*HIDq, wT + (size_t)col0*HIDq, As, Bs, t, wv, lane, wr, wc, lr, g, acc);
    #pragma unroll
    for (int n=0;n<4;n++){
      #pragma unroll
      for (int m=0;m<4;m++){
        int row = row0 + wr + m*16 + lr;
        int b_ = row>>11, ss = row&2047;
        int colb = col0 + wc + n*16 + g*4;
        int seg = colb>>10, cw = colb&1023;
        int hh = cw>>6, d = cw&63;
        const float* bp = seg ? k_b : q_b;
        f32x4 bb = *(const f32x4*)&bp[cw];
        float sc = seg ? 1.0f : (d < 32 ? VS : -LOG2E);
        unsigned short* E = seg ? Keff : Qeff;
        float v0 = (acc[n][m][0]+bb[0])*sc, v1 = (acc[n][m][1]+bb[1])*sc;
        float v2 = (acc[n][m][2]+bb[2])*sc, v3 = (acc[n][m][3]+bb[3])*sc;
        union { unsigned u[2]; unsigned long long ll; } W;
        W.u[0] = pk2bf(v0,v1); W.u[1] = pk2bf(v2,v3);
        *(unsigned long long*)&E[(((size_t)b_*NHh+hh)*Sq+ss)*HDq + d] = W.ll;
      }
    }
  } else {
    const int row0 = (xb-16)*128, col0 = yb*128;
    gemm_core_gl(wT + (size_t)2*HIDq*HIDq + (size_t)row0*HIDq, xbf + (size_t)col0*HIDq,
                 As, Bs, t, wv, lane, wr, wc, lr, g, acc);
    #pragma unroll
    for (int n=0;n<4;n++){
      #pragma unroll
      for (int m=0;m<4;m++){
        int chan = row0 + wr + m*16 + lr;
        int hh = chan>>6, d = chan&63;
        float bv = v_b[chan];
        int colb = col0 + wc + n*16 + g*4;
        int b_ = colb>>11, ss = colb&2047;
        i32x4 mk = *(const i32x4*)&mask[(size_t)b_*Sq + ss];   // zero masked V rows
        float m0 = mk[0]?1.f:0.f, m1 = mk[1]?1.f:0.f, m2 = mk[2]?1.f:0.f, m3 = mk[3]?1.f:0.f;
        union { unsigned u[2]; unsigned long long ll; } W;
        W.u[0] = pk2bf((acc[n][m][0]+bv)*m0, (acc[n][m][1]+bv)*m1);
        W.u[1] = pk2bf((acc[n][m][2]+bv)*m2, (acc[n][m][3]+bv)*m3);
        *(unsigned long long*)&Vt[(((size_t)b_*NHh+hh)*HDq + d)*Sq + ss] = W.ll;
      }
    }
  }
}

// ------------- output projection: 128x64 tile, grid 512 (2 blocks/CU) -------------
__global__ __launch_bounds__(256) void gemm_out(const unsigned short* __restrict__ A,
                                                const unsigned short* __restrict__ Bt,
                                                const float* __restrict__ bias,
                                                float* __restrict__ C){
  __shared__ unsigned short As[128*64];   // 16 KB
  __shared__ unsigned short Bs[64*64];    // 8 KB
  const int t = threadIdx.x;
  const int wv = t>>6, lane = t&63, g = lane>>4, lr = lane&15;
  const int wr = (wv>>1)*64, wc = (wv&1)*32;
  const int row0 = blockIdx.y*128, col0 = blockIdx.x*64;
  f32x4 acc[2][4] = {};
  for (int k0=0; k0<HIDq; k0+=64){
    __syncthreads();
    #pragma unroll
    for (int j=0;j<4;j++){
      int flat = t + j*256;
      int row = flat>>3, c = flat&7;
      int srcc = (c ^ (row&7))*8;
      gload_lds16(A + (size_t)(row0+row)*HIDq + k0 + srcc, &As[flat*8]);
    }
    #pragma unroll
    for (int j=0;j<2;j++){
      int flat = t + j*256;
      int row = flat>>3, c = flat&7;
      int srcc = (c ^ (row&7))*8;
      gload_lds16(Bt + (size_t)(col0+row)*HIDq + k0 + srcc, &Bs[flat*8]);
    }
    __syncthreads();
    #pragma unroll
    for (int ks=0; ks<2; ks++){
      bf16x8 af[4], bfv[2];
      #pragma unroll
      for (int m=0;m<4;m++){
        int rr = wr + m*16 + lr;
        af[m]  = *(bf16x8*)&As[rr*64 + (((ks*4+g) ^ (rr&7))*8)];
      }
      #pragma unroll
      for (int n=0;n<2;n++){
        int rr = wc + n*16 + lr;
        bfv[n] = *(bf16x8*)&Bs[rr*64 + (((ks*4+g) ^ (rr&7))*8)];
      }
      #pragma unroll
      for (int n=0;n<2;n++)
        #pragma unroll
        for (int m=0;m<4;m++)
          acc[n][m] = __builtin_amdgcn_mfma_f32_16x16x32_bf16(bfv[n], af[m], acc[n][m], 0,0,0);
    }
  }
  #pragma unroll
  for (int n=0;n<2;n++){
    #pragma unroll
    for (int m=0;m<4;m++){
      int row = row0 + wr + m*16 + lr;
      int colb = col0 + wc + n*16 + g*4;
      f32x4 bb = *(const f32x4*)&bias[colb];
      f32x4 o = acc[n][m] + bb;
      *(f32x4*)&C[(size_t)row*HIDq + colb] = o;
    }
  }
}

// ------------- flash attention (R12-verified best): counted-vmcnt, 3K+2V bufs, P-in-reg PV -------------
__global__ __launch_bounds__(256,4) void attn_kernel(
    const unsigned short* __restrict__ Qe, const unsigned short* __restrict__ Ke,
    const unsigned short* __restrict__ Vt, const float* __restrict__ Tb,
    const float* __restrict__ tbias, const unsigned short* __restrict__ Mbf,
    unsigned short* __restrict__ Obuf)
{
  __shared__ __align__(16) unsigned char smem[40960];
  unsigned short* Kb0 = (unsigned short*)smem;             // 8 KB each
  unsigned short* Kb1 = (unsigned short*)(smem + 8192);
  unsigned short* Kb2 = (unsigned short*)(smem + 16384);
  unsigned short* Vb0 = (unsigned short*)(smem + 24576);
  unsigned short* Vb1 = (unsigned short*)(smem + 32768);
  float* qls = (float*)smem;                               // overlay in Kb0..Kb2 (16.5 KB)
  unsigned short* qtls = Vb1;                              // overlay in Vb1 (5 KB)

  const int t = threadIdx.x;
  const int dd = blockIdx.x;
  const int slot = dd>>3, xcd = dd&7;
  const int x = slot & 31;
  const int bh = ((slot>>5)<<3) | xcd;
  const int h = bh & 15, b = bh >> 4;
  const int q0 = x*64;
  const int wv = t>>6, lane = t&63, g = lane>>4, lr = lane&15;

  const unsigned short* Qb  = Qe + (((size_t)b*NHh+h)*Sq + q0)*HDq;
  const unsigned short* Kb  = Ke + ((size_t)b*NHh+h)*(size_t)Sq*HDq;
  const unsigned short* Vtb = Vt + ((size_t)b*NHh+h)*(size_t)HDq*Sq;
  const unsigned short* Mbfb = Mbf + (size_t)b*Sq;

  // ---- prologue: qt = q_type(-log2e-scaled) @ T[h] ----
  {
    int row = t>>2, c8 = (t&3)*8;
    bf16x8 v = *(const bf16x8*)(Qb + (size_t)row*HDq + 32 + c8);
    #pragma unroll
    for (int j=0;j<8;j++) qls[row*33 + c8 + j] = bf2f((unsigned short)v[j]);
  }
  __syncthreads();
  {
    int row = t&63, e0 = (t>>6)*8;
    const float* Th = Tb + (size_t)h*1024;
    float a[8] = {};
    #pragma unroll 4
    for (int d=0; d<32; d++){
      float qd = qls[row*33 + d];
      const f32x4* tp = (const f32x4*)(Th + d*32 + e0);
      f32x4 t0 = tp[0], t1 = tp[1];
      a[0]+=qd*t0[0]; a[1]+=qd*t0[1]; a[2]+=qd*t0[2]; a[3]+=qd*t0[3];
      a[4]+=qd*t1[0]; a[5]+=qd*t1[1]; a[6]+=qd*t1[2]; a[7]+=qd*t1[3];
    }
    __syncthreads();   // qls reads done before qtls (Vb1) written
    union { unsigned u[2]; unsigned long long ll; } W0, W1;
    W0.u[0]=pk2bf(a[0],a[1]); W0.u[1]=pk2bf(a[2],a[3]);
    W1.u[0]=pk2bf(a[4],a[5]); W1.u[1]=pk2bf(a[6],a[7]);
    *(unsigned long long*)&qtls[row*40 + e0]     = W0.ll;
    *(unsigned long long*)&qtls[row*40 + e0 + 4] = W1.ll;
  }
  bf16x8 qvf = *(const bf16x8*)(Qb + (size_t)(wv*16+lr)*HDq + g*8);   // val half (prescaled)
  __syncthreads();
  bf16x8 qtn = *(const bf16x8*)&qtls[(wv*16+lr)*40 + g*8];            // type half (neg-scaled)
  __syncthreads();   // qtn reads done before Vb1 reused by staging

  // ---- prologue staging: K(0)->Kb0, V(0)->Vb0, K(1)->Kb1; drain once ----
  #pragma unroll
  for (int i=0;i<2;i++){
    int c = t + i*256;
    int kr = c>>3, kc = c&7;
    gload_lds16(Kb + (size_t)kr*HDq + ((kc ^ (kr&7))*8), Kb0 + c*8);
    int vd = c>>3, vc = c&7;
    gload_lds16(Vtb + (size_t)vd*Sq + ((vc ^ (vd&7))*8), Vb0 + c*8);
    gload_lds16(Kb + (size_t)(64+kr)*HDq + ((kc ^ (kr&7))*8), Kb1 + c*8);
  }
  __syncthreads();   // one full drain at block start only

  const float tbn = -tbias[h]*LOG2E;
  const f32x4 tbc = {tbn,tbn,tbn,tbn};
  const f32x4 zf = {0.f,0.f,0.f,0.f};
  f32x4 oT[4] = {};                 // oT[db][r] = O[q=4g+r][d=db*16+lr]
  f32x4 lsum = {0.f,0.f,0.f,0.f};   // lsum[r] for q=4g+r

  auto phase = [&](const unsigned short* Kc, const unsigned short* Vc, int key0,
                   bool stK, int keyK, unsigned short* Kn,
                   bool stV, int keyV, unsigned short* Vn, bool vm8){
    if (stK){
      #pragma unroll
      for (int i=0;i<2;i++){
        int c = t + i*256;
        int kr = c>>3, kc = c&7;
        gload_lds16(Kb + (size_t)(keyK+kr)*HDq + ((kc ^ (kr&7))*8), Kn + c*8);
      }
    }
    if (stV){
      #pragma unroll
      for (int i=0;i<2;i++){
        int c = t + i*256;
        int vd = c>>3, vc = c&7;
        gload_lds16(Vtb + (size_t)vd*Sq + keyV + ((vc ^ (vd&7))*8), Vn + c*8);
      }
    }
    if (vm8) asm volatile("s_waitcnt vmcnt(8)" ::: "memory");
    else     asm volatile("s_waitcnt vmcnt(4)" ::: "memory");
    __builtin_amdgcn_sched_barrier(0);
    __builtin_amdgcn_s_barrier();        // all waves' tile-i stages landed

    // QK^T swapped: lane holds P[q=lr][k = 16ks+4g+r]
    f32x4 sv[4], st[4];
    __builtin_amdgcn_s_setprio(1);
    #pragma unroll
    for (int ks=0; ks<4; ks++){
      const unsigned short* kb = Kc + (ks*16+lr)*64;
      bf16x8 kf0 = *(const bf16x8*)(kb + (((g  ) ^ (lr&7))*8));
      bf16x8 kf1 = *(const bf16x8*)(kb + (((4+g) ^ (lr&7))*8));
      sv[ks] = __builtin_amdgcn_mfma_f32_16x16x32_bf16(kf0, qvf, zf, 0,0,0);
      st[ks] = __builtin_amdgcn_mfma_f32_16x16x32_bf16(kf1, qtn, tbc, 0,0,0);
    }
    __builtin_amdgcn_s_setprio(0);
    // p = exp2(sv) * sigmoid2(st); pack into x16 A-fragments (q=lr, k_local=4g+j)
    bf16x4 pa[4];
    #pragma unroll
    for (int ks=0; ks<4; ks++){
      float p0 = EXP2F(sv[ks][0]) * RCPF(1.f + EXP2F(st[ks][0]));
      float p1 = EXP2F(sv[ks][1]) * RCPF(1.f + EXP2F(st[ks][1]));
      float p2 = EXP2F(sv[ks][2]) * RCPF(1.f + EXP2F(st[ks][2]));
      float p3 = EXP2F(sv[ks][3]) * RCPF(1.f + EXP2F(st[ks][3]));
      union { unsigned u[2]; bf16x4 v; } P_;
      P_.u[0] = pk2bf(p0,p1); P_.u[1] = pk2bf(p2,p3);
      pa[ks] = P_.v;
    }
    // PV: O[q][d] += P[q][k] V[k][d] via 16x16x16; lsum via mask B-fragment
    #pragma unroll
    for (int ks=0; ks<4; ks++){
      bf16x4 mfr = *(const bf16x4*)(Mbfb + key0 + ks*16 + g*4);
      __builtin_amdgcn_s_setprio(1);
      lsum = MFMA16(pa[ks], mfr, lsum);
      #pragma unroll
      for (int db=0; db<4; db++){
        bf16x4 vf = *(const bf16x4*)(Vc + (db*16+lr)*64 + (((2*ks + (g>>1)) ^ (lr&7))*8 + 4*(g&1)));
        oT[db] = MFMA16(pa[ks], vf, oT[db]);
      }
      __builtin_amdgcn_s_setprio(0);
    }
    __builtin_amdgcn_s_barrier();        // readers done before bufs reused
  };

  // 30 phases in 5 groups of 6 (K buffers period 3, V buffers period 2), then 2 tail phases
  for (int j=0; j<5; j++){
    int kt = j*384;
    phase(Kb0, Vb0, kt,      true, kt+128, Kb2,  true, kt+64,  Vb1, true);
    phase(Kb1, Vb1, kt+64,   true, kt+192, Kb0,  true, kt+128, Vb0, true);
    phase(Kb2, Vb0, kt+128,  true, kt+256, Kb1,  true, kt+192, Vb1, true);
    phase(Kb0, Vb1, kt+192,  true, kt+320, Kb2,  true, kt+256, Vb0, true);
    phase(Kb1, Vb0, kt+256,  true, kt+384, Kb0,  true, kt+320, Vb1, true);
    phase(Kb2, Vb1, kt+320,  (kt+448 < Sq), kt+448, Kb1,  true, kt+384, Vb0, true);
  }
  phase(Kb0, Vb0, 1920,  false, 0, Kb0,  true, 1984, Vb1, false);   // i=30
  phase(Kb1, Vb1, 1984,  false, 0, Kb0,  false, 0, Vb0,  false);    // i=31

  // ---- epilogue: lane (g,lr) holds O[q = wv*16+4g+r][d = db*16+lr] ----
  float linv[4];
  #pragma unroll
  for (int r=0;r<4;r++) linv[r] = (lsum[r] > 0.f) ? RCPF(lsum[r]) : 0.f;
  unsigned short* Ob = Obuf + ((size_t)b*Sq + (q0 + wv*16 + g*4))*HIDq + h*HDq + lr;
  #pragma unroll
  for (int db=0; db<4; db++){
    #pragma unroll
    for (int r=0;r<4;r++)
      Ob[(size_t)r*HIDq + db*16] = f2bf(oT[db][r]*linv[r]);
  }
}

extern "C" void kernel_launch(void* const* d_in, const int* in_sizes, int n_in,
                              void* d_out, int out_size, void* d_ws, size_t ws_size,
                              hipStream_t stream) {
  const float* x     = (const float*)d_in[0];
  const float* q_w   = (const float*)d_in[1];
  const float* q_b   = (const float*)d_in[2];
  const float* k_w   = (const float*)d_in[3];
  const float* k_b   = (const float*)d_in[4];
  const float* v_w   = (const float*)d_in[5];
  const float* v_b   = (const float*)d_in[6];
  const float* out_w = (const float*)d_in[7];
  const float* out_b = (const float*)d_in[8];
  const float* Tb    = (const float*)d_in[9];
  const float* tbias = (const float*)d_in[10];
  const int*   mask  = (const int*)d_in[11];

  const size_t MROWS = 4096;             // B*S
  unsigned short* xbf  = (unsigned short*)d_ws;           // 4M shorts
  unsigned short* wT   = xbf  + MROWS*HIDq;               // 4 x 1M
  unsigned short* Qeff = wT   + (size_t)4*HIDq*HIDq;      // (B,NH,S,HD), prescaled
  unsigned short* Keff = Qeff + MROWS*HIDq;
  unsigned short* Vt   = Keff + MROWS*HIDq;               // (B,NH,HD,S) transposed, masked rows zeroed
  unsigned short* Obuf = Vt   + MROWS*HIDq;               // (B,S,HID) bf16
  unsigned short* Mbf  = Obuf + MROWS*HIDq;               // (B,S) bf16 0/1 mask

  prep<<<dim3(6146), dim3(256), 0, stream>>>(x, xbf, mask, Mbf, q_w, k_w, v_w, out_w, wT);

  gemm_qkv<<<dim3(768), dim3(256), 0, stream>>>(xbf, wT, q_b, k_b, v_b, mask, Qeff, Keff, Vt);

  attn_kernel<<<dim3(1024), dim3(256), 0, stream>>>(Qeff, Keff, Vt, Tb, tbias, Mbf, Obuf);

  gemm_out<<<dim3(16,32), dim3(256), 0, stream>>>(Obuf, wT + (size_t)3*HIDq*HIDq, out_b, (float*)d_out);
}